// Round 2
// baseline (11215.260 us; speedup 1.0000x reference)
//
#include <hip/hip_runtime.h>

// MPNN on MI355X — fp32 vector-ALU.
//
// Algebraic restructure: msg layer-1 is linear before the relu, so
//   m1 = relu(P[dst] + Q[src] + ea@W1e + b1),  P = h@W1[0:64], Q = h@W1[64:128]
// moving 128 of the 134 K-rows from per-edge (800k) to per-node (50k) work.
//
// R2: k_edge is edge-per-LANE (was edge-per-wave + readlane broadcast).
// Weights become wave-uniform -> s_load; inner loop is pure v_fmac with one
// SGPR operand (1 instr/MAC instead of 2). acc[64] lives in VGPRs.

__device__ __forceinline__ float bcast(float v, int lane) {
    return __int_as_float(__builtin_amdgcn_readlane(__float_as_int(v), lane));
}

// h = x @ Win + b   (x: n x 128, Win: 128 x 64)
__global__ __launch_bounds__(256) void k_in(const float* __restrict__ x,
        const float* __restrict__ w, const float* __restrict__ b,
        float* __restrict__ h, int nNodes) {
    const int lane = threadIdx.x & 63;
    const int wid  = blockIdx.x * (blockDim.x >> 6) + (threadIdx.x >> 6);
    const int nw   = gridDim.x * (blockDim.x >> 6);
    float wa[64], wb[64];
#pragma unroll
    for (int k = 0; k < 64; ++k) wa[k] = w[k * 64 + lane];
#pragma unroll
    for (int k = 0; k < 64; ++k) wb[k] = w[(64 + k) * 64 + lane];
    const float bc = b[lane];
    for (int n = wid; n < nNodes; n += nw) {
        float x0 = x[(long)n * 128 + lane];
        float x1 = x[(long)n * 128 + 64 + lane];
        float acc = bc;
#pragma unroll
        for (int k = 0; k < 64; ++k) acc += bcast(x0, k) * wa[k];
#pragma unroll
        for (int k = 0; k < 64; ++k) acc += bcast(x1, k) * wb[k];
        h[(long)n * 64 + lane] = acc;
    }
}

// P = h @ W1[0:64], Q = h @ W1[64:128]   (no bias here)
__global__ __launch_bounds__(256) void k_pre(const float* __restrict__ h,
        const float* __restrict__ w1, float* __restrict__ P, float* __restrict__ Q,
        int nNodes) {
    const int lane = threadIdx.x & 63;
    const int wid  = blockIdx.x * (blockDim.x >> 6) + (threadIdx.x >> 6);
    const int nw   = gridDim.x * (blockDim.x >> 6);
    float wa[64], wb[64];
#pragma unroll
    for (int k = 0; k < 64; ++k) wa[k] = w1[k * 64 + lane];
#pragma unroll
    for (int k = 0; k < 64; ++k) wb[k] = w1[(64 + k) * 64 + lane];
    for (int n = wid; n < nNodes; n += nw) {
        float hv = h[(long)n * 64 + lane];
        float accP = 0.f, accQ = 0.f;
#pragma unroll
        for (int k = 0; k < 64; ++k) {
            float s = bcast(hv, k);
            accP += s * wa[k];
            accQ += s * wb[k];
        }
        P[(long)n * 64 + lane] = accP;
        Q[(long)n * 64 + lane] = accQ;
    }
}

// per-edge (one EDGE per LANE):
//   m1 = relu(P[dst]+Q[src]+ea@W1e+b1); m2 = relu(m1@W2+b2); agg[dst] += m2
// Weights indexed wave-uniformly -> scalar loads; inner loop pure v_fmac.
__global__ __launch_bounds__(256) void k_edge(const float* __restrict__ P,
        const float* __restrict__ Q, const float* __restrict__ ea,
        const int* __restrict__ src, const int* __restrict__ dst,
        const float* __restrict__ w1e, const float* __restrict__ b1,
        const float* __restrict__ w2, const float* __restrict__ b2,
        float* __restrict__ agg, int nEdges) {
    const int e0     = blockIdx.x * blockDim.x + threadIdx.x;
    const int stride = gridDim.x * blockDim.x;
    for (int e = e0; e < nEdges; e += stride) {
        const int s = src[e];
        const int d = dst[e];
        const float4* __restrict__ Pd4 = (const float4*)(P + (size_t)d * 64);
        const float4* __restrict__ Qs4 = (const float4*)(Q + (size_t)s * 64);
        float eav[6];
#pragma unroll
        for (int j = 0; j < 6; ++j) eav[j] = ea[(size_t)e * 6 + j];
        float acc[64];
#pragma unroll
        for (int c = 0; c < 64; ++c) acc[c] = b2[c];
        for (int kc = 0; kc < 8; ++kc) {      // NOT unrolled: keeps code ~5KB
            float4 p0 = Pd4[2 * kc], p1 = Pd4[2 * kc + 1];
            float4 q0 = Qs4[2 * kc], q1 = Qs4[2 * kc + 1];
            float m1c[8];
            m1c[0] = p0.x + q0.x; m1c[1] = p0.y + q0.y;
            m1c[2] = p0.z + q0.z; m1c[3] = p0.w + q0.w;
            m1c[4] = p1.x + q1.x; m1c[5] = p1.y + q1.y;
            m1c[6] = p1.z + q1.z; m1c[7] = p1.w + q1.w;
#pragma unroll
            for (int j = 0; j < 8; ++j) {
                const int k = kc * 8 + j;
                float t = m1c[j] + b1[k];
#pragma unroll
                for (int jj = 0; jj < 6; ++jj)
                    t = fmaf(eav[jj], w1e[jj * 64 + k], t);
                m1c[j] = fmaxf(t, 0.f);
            }
#pragma unroll
            for (int j = 0; j < 8; ++j) {
#pragma unroll
                for (int c = 0; c < 64; ++c)
                    acc[c] = fmaf(m1c[j], w2[(kc * 8 + j) * 64 + c], acc[c]);
            }
        }
        float* __restrict__ ag = agg + (size_t)d * 64;
#pragma unroll
        for (int c = 0; c < 64; ++c)
            atomicAdd(&ag[c], fmaxf(acc[c], 0.f));
    }
}

// tmp = relu([h, agg] @ U1 + b1)
__global__ __launch_bounds__(256) void k_upd1(const float* __restrict__ h,
        const float* __restrict__ agg, const float* __restrict__ w,
        const float* __restrict__ b, float* __restrict__ tmp, int nNodes) {
    const int lane = threadIdx.x & 63;
    const int wid  = blockIdx.x * (blockDim.x >> 6) + (threadIdx.x >> 6);
    const int nw   = gridDim.x * (blockDim.x >> 6);
    float wa[64], wb[64];
#pragma unroll
    for (int k = 0; k < 64; ++k) wa[k] = w[k * 64 + lane];
#pragma unroll
    for (int k = 0; k < 64; ++k) wb[k] = w[(64 + k) * 64 + lane];
    const float bc = b[lane];
    for (int n = wid; n < nNodes; n += nw) {
        float hv = h[(long)n * 64 + lane];
        float av = agg[(long)n * 64 + lane];
        float acc = bc;
#pragma unroll
        for (int k = 0; k < 64; ++k) acc += bcast(hv, k) * wa[k];
#pragma unroll
        for (int k = 0; k < 64; ++k) acc += bcast(av, k) * wb[k];
        tmp[(long)n * 64 + lane] = fmaxf(acc, 0.f);
    }
}

// h += relu(tmp @ U2 + b2)
__global__ __launch_bounds__(256) void k_upd2(float* __restrict__ h,
        const float* __restrict__ tmp, const float* __restrict__ w,
        const float* __restrict__ b, int nNodes) {
    const int lane = threadIdx.x & 63;
    const int wid  = blockIdx.x * (blockDim.x >> 6) + (threadIdx.x >> 6);
    const int nw   = gridDim.x * (blockDim.x >> 6);
    float w2c[64];
#pragma unroll
    for (int k = 0; k < 64; ++k) w2c[k] = w[k * 64 + lane];
    const float bc = b[lane];
    for (int n = wid; n < nNodes; n += nw) {
        float tv = tmp[(long)n * 64 + lane];
        float acc = bc;
#pragma unroll
        for (int k = 0; k < 64; ++k) acc += bcast(tv, k) * w2c[k];
        h[(long)n * 64 + lane] += fmaxf(acc, 0.f);
    }
}

// colsum[c] += sum_n h[n][c]
__global__ __launch_bounds__(256) void k_colsum(const float* __restrict__ h,
        float* __restrict__ colsum, int nNodes) {
    const int lane = threadIdx.x & 63;
    const int wid  = blockIdx.x * 4 + (threadIdx.x >> 6);
    const int nw   = gridDim.x * 4;
    float s = 0.f;
    for (int n = wid; n < nNodes; n += nw) s += h[(long)n * 64 + lane];
    __shared__ float sm[64];
    if (threadIdx.x < 64) sm[threadIdx.x] = 0.f;
    __syncthreads();
    atomicAdd(&sm[lane], s);
    __syncthreads();
    if (threadIdx.x < 64) atomicAdd(&colsum[threadIdx.x], sm[threadIdx.x]);
}

// out[0] = dot(colsum, pred_w) + nNodes * pred_b
__global__ void k_out(const float* __restrict__ colsum, const float* __restrict__ pw,
                      const float* __restrict__ pb, float* __restrict__ out, int nNodes) {
    const int lane = threadIdx.x;
    float v = colsum[lane] * pw[lane];
#pragma unroll
    for (int off = 32; off; off >>= 1) v += __shfl_down(v, off);
    if (lane == 0) out[0] = v + (float)nNodes * pb[0];
}

extern "C" void kernel_launch(void* const* d_in, const int* in_sizes, int n_in,
                              void* d_out, int out_size, void* d_ws, size_t ws_size,
                              hipStream_t stream) {
    const float* x     = (const float*)d_in[0];
    const int*   ei    = (const int*)d_in[1];
    const float* ea    = (const float*)d_in[2];
    const float* lin_w = (const float*)d_in[3];
    const float* lin_b = (const float*)d_in[4];
    const float* mw1   = (const float*)d_in[5];
    const float* mb1   = (const float*)d_in[6];
    const float* mw2   = (const float*)d_in[7];
    const float* mb2   = (const float*)d_in[8];
    const float* uw1   = (const float*)d_in[9];
    const float* ub1   = (const float*)d_in[10];
    const float* uw2   = (const float*)d_in[11];
    const float* ub2   = (const float*)d_in[12];
    const float* pw    = (const float*)d_in[13];
    const float* pb    = (const float*)d_in[14];

    const int nNodes = in_sizes[0] / 128;
    const int nEdges = in_sizes[1] / 2;
    const int* src = ei;            // edge_index[0]
    const int* dst = ei + nEdges;   // edge_index[1]

    float* h      = (float*)d_ws;
    float* P      = h + (size_t)nNodes * 64;
    float* Q      = P + (size_t)nNodes * 64;
    float* agg    = Q + (size_t)nNodes * 64;
    float* colsum = agg + (size_t)nNodes * 64;

    const int NB_NODE = 1024;
    const int NB_EDGE = (nEdges + 255) / 256;   // one edge per thread

    k_in<<<NB_NODE, 256, 0, stream>>>(x, lin_w, lin_b, h, nNodes);

    for (int l = 0; l < 4; ++l) {
        const float* w1 = mw1 + (size_t)l * 134 * 64;
        k_pre<<<NB_NODE, 256, 0, stream>>>(h, w1, P, Q, nNodes);
        hipMemsetAsync(agg, 0, (size_t)nNodes * 64 * sizeof(float), stream);
        k_edge<<<NB_EDGE, 256, 0, stream>>>(P, Q, ea, src, dst,
            w1 + 128 * 64, mb1 + l * 64,
            mw2 + (size_t)l * 64 * 64, mb2 + l * 64, agg, nEdges);
        k_upd1<<<NB_NODE, 256, 0, stream>>>(h, agg,
            uw1 + (size_t)l * 128 * 64, ub1 + l * 64, P, nNodes);
        k_upd2<<<NB_NODE, 256, 0, stream>>>(h, P,
            uw2 + (size_t)l * 64 * 64, ub2 + l * 64, nNodes);
    }

    hipMemsetAsync(colsum, 0, 64 * sizeof(float), stream);
    k_colsum<<<512, 256, 0, stream>>>(h, colsum, nNodes);
    k_out<<<1, 64, 0, stream>>>(colsum, pw, pb, (float*)d_out, nNodes);
}

// Round 3
// 1200.339 us; speedup vs baseline: 9.3434x; 9.3434x over previous
//
#include <hip/hip_runtime.h>

// MPNN on MI355X.
//
// Algebraic restructure: msg layer-1 is linear before the relu, so
//   m1 = relu(P[dst] + Q[src] + ea@W1e + b1),  P = h@W1[0:64], Q = h@W1[64:128]
// moving 128 of the 134 K-rows from per-edge (800k) to per-node (50k) work.
//
// R3: k_edge computes the m2 GEMM (edges x 64 @ 64 x 64) with bf16 MFMA,
// 16 edges per wave. W2 is split hi+lo bf16 (systematic-rounding-free);
// m1 is rounded to bf16 (random rounding, cancels in the global sum).
// R2's per-lane acc[64] spilled to scratch (VGPR_Count=48, WRITE 1.6GB) —
// abandoned.

typedef __attribute__((ext_vector_type(8))) short short8;
typedef __attribute__((ext_vector_type(4))) float float4v;

__device__ __forceinline__ float bcast(float v, int lane) {
    return __int_as_float(__builtin_amdgcn_readlane(__float_as_int(v), lane));
}

__device__ __forceinline__ unsigned short f2bf(float f) {
    unsigned int u = __float_as_uint(f);
    unsigned int r = u + 0x7fff + ((u >> 16) & 1);   // RTNE
    return (unsigned short)(r >> 16);
}

// h = x @ Win + b   (x: n x 128, Win: 128 x 64)
__global__ __launch_bounds__(256) void k_in(const float* __restrict__ x,
        const float* __restrict__ w, const float* __restrict__ b,
        float* __restrict__ h, int nNodes) {
    const int lane = threadIdx.x & 63;
    const int wid  = blockIdx.x * (blockDim.x >> 6) + (threadIdx.x >> 6);
    const int nw   = gridDim.x * (blockDim.x >> 6);
    float wa[64], wb[64];
#pragma unroll
    for (int k = 0; k < 64; ++k) wa[k] = w[k * 64 + lane];
#pragma unroll
    for (int k = 0; k < 64; ++k) wb[k] = w[(64 + k) * 64 + lane];
    const float bc = b[lane];
    for (int n = wid; n < nNodes; n += nw) {
        float x0 = x[(long)n * 128 + lane];
        float x1 = x[(long)n * 128 + 64 + lane];
        float acc = bc;
#pragma unroll
        for (int k = 0; k < 64; ++k) acc += bcast(x0, k) * wa[k];
#pragma unroll
        for (int k = 0; k < 64; ++k) acc += bcast(x1, k) * wb[k];
        h[(long)n * 64 + lane] = acc;
    }
}

// P = h @ W1[0:64], Q = h @ W1[64:128]
__global__ __launch_bounds__(256) void k_pre(const float* __restrict__ h,
        const float* __restrict__ w1, float* __restrict__ P, float* __restrict__ Q,
        int nNodes) {
    const int lane = threadIdx.x & 63;
    const int wid  = blockIdx.x * (blockDim.x >> 6) + (threadIdx.x >> 6);
    const int nw   = gridDim.x * (blockDim.x >> 6);
    float wa[64], wb[64];
#pragma unroll
    for (int k = 0; k < 64; ++k) wa[k] = w1[k * 64 + lane];
#pragma unroll
    for (int k = 0; k < 64; ++k) wb[k] = w1[(64 + k) * 64 + lane];
    for (int n = wid; n < nNodes; n += nw) {
        float hv = h[(long)n * 64 + lane];
        float accP = 0.f, accQ = 0.f;
#pragma unroll
        for (int k = 0; k < 64; ++k) {
            float s = bcast(hv, k);
            accP += s * wa[k];
            accQ += s * wb[k];
        }
        P[(long)n * 64 + lane] = accP;
        Q[(long)n * 64 + lane] = accQ;
    }
}

// ---- edge kernel: 16 edges per wave, m2 GEMM via bf16 MFMA ----
// m1 = relu(P[dst]+Q[src]+ea@W1e+b1)  (fp32, wave-coalesced rows)
// m2 = relu(m1 @ (W2hi+W2lo) + b2)    (MFMA 16x16x32 bf16, W2 split)
// agg[dst] += m2                      (atomic, C-layout coalesced)
#define M1_STRIDE 72   // ushorts; 144B rows -> 2-way LDS bank aliasing (free)

__global__ __launch_bounds__(256) void k_edge(const float* __restrict__ P,
        const float* __restrict__ Q, const float* __restrict__ ea,
        const int* __restrict__ src, const int* __restrict__ dst,
        const float* __restrict__ w1e, const float* __restrict__ b1,
        const float* __restrict__ w2, const float* __restrict__ b2,
        float* __restrict__ agg, int nEdges) {
    const int lane = threadIdx.x & 63;
    const int wib  = threadIdx.x >> 6;              // wave in block
    const int wid  = blockIdx.x * 4 + wib;
    const int nw   = gridDim.x * 4;
    const int quad = lane >> 4;
    const int col  = lane & 15;

    __shared__ unsigned short m1b[4][16 * M1_STRIDE];
    unsigned short* __restrict__ mt = m1b[wib];

    // per-lane (column = lane) constants for the m1 stage
    float w1ec[6];
#pragma unroll
    for (int j = 0; j < 6; ++j) w1ec[j] = w1e[j * 64 + lane];
    const float b1c = b1[lane];

    // B fragments: W2[k][n], frag elem j = W2[kh*32+quad*8+j][nt*16+col], hi/lo split
    short8 bhi[4][2], blo[4][2];
#pragma unroll
    for (int nt = 0; nt < 4; ++nt)
#pragma unroll
        for (int kh = 0; kh < 2; ++kh)
#pragma unroll
            for (int j = 0; j < 8; ++j) {
                float wv = w2[(kh * 32 + quad * 8 + j) * 64 + nt * 16 + col];
                unsigned short hi = f2bf(wv);
                float whif = __uint_as_float(((unsigned int)hi) << 16);
                unsigned short lo = f2bf(wv - whif);
                bhi[nt][kh][j] = (short)hi;
                blo[nt][kh][j] = (short)lo;
            }
    // b2 per N-tile (indexed by this lane's C column)
    float b2v[4];
#pragma unroll
    for (int nt = 0; nt < 4; ++nt) b2v[nt] = b2[nt * 16 + col];

    const int nBatch = (nEdges + 15) >> 4;
    for (int bt = wid; bt < nBatch; bt += nw) {
        const int base = __builtin_amdgcn_readfirstlane(bt << 4);

        // ---- stage m1 rows (16 edges), fp32 -> bf16 -> LDS ----
        for (int j = 0; j < 16; ++j) {
            int e = base + j;
            if (e >= nEdges) e = nEdges - 1;       // uniform clamp (tail)
            const int s = src[e];
            const int d = dst[e];
            float t = P[(size_t)d * 64 + lane] + Q[(size_t)s * 64 + lane] + b1c;
            const float* eap = ea + (size_t)e * 6;
#pragma unroll
            for (int jj = 0; jj < 6; ++jj) t = fmaf(eap[jj], w1ec[jj], t);
            mt[j * M1_STRIDE + lane] = f2bf(fmaxf(t, 0.f));
        }
        __builtin_amdgcn_s_waitcnt(0);             // drain lgkm (wave-local LDS)

        // ---- A fragments: A[m=lane&15][k=quad*8+j] ----
        const int row = col;                        // A-row = edge index in batch
        short8 a0 = *(const short8*)&mt[row * M1_STRIDE + quad * 8];
        short8 a1 = *(const short8*)&mt[row * M1_STRIDE + 32 + quad * 8];

        // ---- MFMA: 4 N-tiles x 2 K-halves x (hi+lo) ----
        float4v acc[4];
#pragma unroll
        for (int nt = 0; nt < 4; ++nt) {
            float4v c = {0.f, 0.f, 0.f, 0.f};
            c = __builtin_amdgcn_mfma_f32_16x16x32_bf16(a0, bhi[nt][0], c, 0, 0, 0);
            c = __builtin_amdgcn_mfma_f32_16x16x32_bf16(a1, bhi[nt][1], c, 0, 0, 0);
            c = __builtin_amdgcn_mfma_f32_16x16x32_bf16(a0, blo[nt][0], c, 0, 0, 0);
            c = __builtin_amdgcn_mfma_f32_16x16x32_bf16(a1, blo[nt][1], c, 0, 0, 0);
            acc[nt] = c;
        }

        // ---- epilogue: +b2, relu, atomic scatter-add ----
        // C layout: col = lane&15, row(edge) = quad*4 + r
#pragma unroll
        for (int r = 0; r < 4; ++r) {
            const int erow = base + quad * 4 + r;
            if (erow < nEdges) {
                const int d = dst[erow];
                float* __restrict__ ag = agg + (size_t)d * 64;
#pragma unroll
                for (int nt = 0; nt < 4; ++nt) {
                    float v = fmaxf(acc[nt][r] + b2v[nt], 0.f);
                    atomicAdd(&ag[nt * 16 + col], v);
                }
            }
        }
    }
}

// tmp = relu([h, agg] @ U1 + b1)
__global__ __launch_bounds__(256) void k_upd1(const float* __restrict__ h,
        const float* __restrict__ agg, const float* __restrict__ w,
        const float* __restrict__ b, float* __restrict__ tmp, int nNodes) {
    const int lane = threadIdx.x & 63;
    const int wid  = blockIdx.x * (blockDim.x >> 6) + (threadIdx.x >> 6);
    const int nw   = gridDim.x * (blockDim.x >> 6);
    float wa[64], wb[64];
#pragma unroll
    for (int k = 0; k < 64; ++k) wa[k] = w[k * 64 + lane];
#pragma unroll
    for (int k = 0; k < 64; ++k) wb[k] = w[(64 + k) * 64 + lane];
    const float bc = b[lane];
    for (int n = wid; n < nNodes; n += nw) {
        float hv = h[(long)n * 64 + lane];
        float av = agg[(long)n * 64 + lane];
        float acc = bc;
#pragma unroll
        for (int k = 0; k < 64; ++k) acc += bcast(hv, k) * wa[k];
#pragma unroll
        for (int k = 0; k < 64; ++k) acc += bcast(av, k) * wb[k];
        tmp[(long)n * 64 + lane] = fmaxf(acc, 0.f);
    }
}

// h += relu(tmp @ U2 + b2)
__global__ __launch_bounds__(256) void k_upd2(float* __restrict__ h,
        const float* __restrict__ tmp, const float* __restrict__ w,
        const float* __restrict__ b, int nNodes) {
    const int lane = threadIdx.x & 63;
    const int wid  = blockIdx.x * (blockDim.x >> 6) + (threadIdx.x >> 6);
    const int nw   = gridDim.x * (blockDim.x >> 6);
    float w2c[64];
#pragma unroll
    for (int k = 0; k < 64; ++k) w2c[k] = w[k * 64 + lane];
    const float bc = b[lane];
    for (int n = wid; n < nNodes; n += nw) {
        float tv = tmp[(long)n * 64 + lane];
        float acc = bc;
#pragma unroll
        for (int k = 0; k < 64; ++k) acc += bcast(tv, k) * w2c[k];
        h[(long)n * 64 + lane] += fmaxf(acc, 0.f);
    }
}

// colsum[c] += sum_n h[n][c]
__global__ __launch_bounds__(256) void k_colsum(const float* __restrict__ h,
        float* __restrict__ colsum, int nNodes) {
    const int lane = threadIdx.x & 63;
    const int wid  = blockIdx.x * 4 + (threadIdx.x >> 6);
    const int nw   = gridDim.x * 4;
    float s = 0.f;
    for (int n = wid; n < nNodes; n += nw) s += h[(long)n * 64 + lane];
    __shared__ float sm[64];
    if (threadIdx.x < 64) sm[threadIdx.x] = 0.f;
    __syncthreads();
    atomicAdd(&sm[lane], s);
    __syncthreads();
    if (threadIdx.x < 64) atomicAdd(&colsum[threadIdx.x], sm[threadIdx.x]);
}

// out[0] = dot(colsum, pred_w) + nNodes * pred_b
__global__ void k_out(const float* __restrict__ colsum, const float* __restrict__ pw,
                      const float* __restrict__ pb, float* __restrict__ out, int nNodes) {
    const int lane = threadIdx.x;
    float v = colsum[lane] * pw[lane];
#pragma unroll
    for (int off = 32; off; off >>= 1) v += __shfl_down(v, off);
    if (lane == 0) out[0] = v + (float)nNodes * pb[0];
}

extern "C" void kernel_launch(void* const* d_in, const int* in_sizes, int n_in,
                              void* d_out, int out_size, void* d_ws, size_t ws_size,
                              hipStream_t stream) {
    const float* x     = (const float*)d_in[0];
    const int*   ei    = (const int*)d_in[1];
    const float* ea    = (const float*)d_in[2];
    const float* lin_w = (const float*)d_in[3];
    const float* lin_b = (const float*)d_in[4];
    const float* mw1   = (const float*)d_in[5];
    const float* mb1   = (const float*)d_in[6];
    const float* mw2   = (const float*)d_in[7];
    const float* mb2   = (const float*)d_in[8];
    const float* uw1   = (const float*)d_in[9];
    const float* ub1   = (const float*)d_in[10];
    const float* uw2   = (const float*)d_in[11];
    const float* ub2   = (const float*)d_in[12];
    const float* pw    = (const float*)d_in[13];
    const float* pb    = (const float*)d_in[14];

    const int nNodes = in_sizes[0] / 128;
    const int nEdges = in_sizes[1] / 2;
    const int* src = ei;            // edge_index[0]
    const int* dst = ei + nEdges;   // edge_index[1]

    float* h      = (float*)d_ws;
    float* P      = h + (size_t)nNodes * 64;
    float* Q      = P + (size_t)nNodes * 64;
    float* agg    = Q + (size_t)nNodes * 64;
    float* colsum = agg + (size_t)nNodes * 64;

    const int NB_NODE = 1024;
    const int NB_EDGE = 1024;   // 4096 waves, ~12 edge-batches each

    k_in<<<NB_NODE, 256, 0, stream>>>(x, lin_w, lin_b, h, nNodes);

    for (int l = 0; l < 4; ++l) {
        const float* w1 = mw1 + (size_t)l * 134 * 64;
        k_pre<<<NB_NODE, 256, 0, stream>>>(h, w1, P, Q, nNodes);
        hipMemsetAsync(agg, 0, (size_t)nNodes * 64 * sizeof(float), stream);
        k_edge<<<NB_EDGE, 256, 0, stream>>>(P, Q, ea, src, dst,
            w1 + 128 * 64, mb1 + l * 64,
            mw2 + (size_t)l * 64 * 64, mb2 + l * 64, agg, nEdges);
        k_upd1<<<NB_NODE, 256, 0, stream>>>(h, agg,
            uw1 + (size_t)l * 128 * 64, ub1 + l * 64, P, nNodes);
        k_upd2<<<NB_NODE, 256, 0, stream>>>(h, P,
            uw2 + (size_t)l * 64 * 64, ub2 + l * 64, nNodes);
    }

    hipMemsetAsync(colsum, 0, 64 * sizeof(float), stream);
    k_colsum<<<512, 256, 0, stream>>>(h, colsum, nNodes);
    k_out<<<1, 64, 0, stream>>>(colsum, pw, pb, (float*)d_out, nNodes);
}

// Round 4
// 1197.343 us; speedup vs baseline: 9.3668x; 1.0025x over previous
//
#include <hip/hip_runtime.h>

// MPNN on MI355X.
//
// Algebra: msg layer-1 is linear before its relu:
//   m1 = relu(P[dst] + Q[src] + ea@W1e + b1), P = h@W1[0:64], Q = h@W1[64:128]
// R3: m2 GEMM via bf16 MFMA (W2 split hi+lo bf16 -> fp32-exact; absmax was 0).
// R4: kill the 51.2M fp32 atomics (TCC RMW throughput floor ~167us/layer,
// WRITE_SIZE == atomic_count*4B). Build dst-sorted CSR once per launch
// (edge_index is layer-invariant), aggregate consumer-side: one wave per dst
// node, C-tile reduced across rows in-register (shfl_xor over quads), one
// plain store per node. agg memsets also gone.

typedef __attribute__((ext_vector_type(8))) short short8;
typedef __attribute__((ext_vector_type(4))) float float4v;

__device__ __forceinline__ float bcast(float v, int lane) {
    return __int_as_float(__builtin_amdgcn_readlane(__float_as_int(v), lane));
}

__device__ __forceinline__ unsigned short f2bf(float f) {
    unsigned int u = __float_as_uint(f);
    unsigned int r = u + 0x7fff + ((u >> 16) & 1);   // RTNE
    return (unsigned short)(r >> 16);
}

// ---------------- CSR build ----------------
__global__ __launch_bounds__(256) void k_hist(const int* __restrict__ dst,
        int* __restrict__ deg, int nEdges) {
    int e = blockIdx.x * blockDim.x + threadIdx.x;
    if (e < nEdges) atomicAdd(&deg[dst[e]], 1);
}

#define SCAN_T 1024
__global__ __launch_bounds__(SCAN_T) void k_scan(const int* __restrict__ deg,
        int* __restrict__ row_ptr, int* __restrict__ cursor, int nNodes) {
    __shared__ int part[SCAN_T];
    const int t = threadIdx.x;
    const int chunk = (nNodes + SCAN_T - 1) / SCAN_T;
    const int lo = t * chunk;
    const int hi = min(lo + chunk, nNodes);
    int s = 0;
    for (int i = lo; i < hi; ++i) s += deg[i];
    part[t] = s;
    __syncthreads();
    for (int off = 1; off < SCAN_T; off <<= 1) {
        int v = (t >= off) ? part[t - off] : 0;
        __syncthreads();
        part[t] += v;
        __syncthreads();
    }
    int run = (t == 0) ? 0 : part[t - 1];
    for (int i = lo; i < hi; ++i) {
        row_ptr[i] = run;
        cursor[i]  = run;
        run += deg[i];
    }
    if (t == SCAN_T - 1) row_ptr[nNodes] = run;
}

__global__ __launch_bounds__(256) void k_scatter(const int* __restrict__ src,
        const int* __restrict__ dst, const float* __restrict__ ea,
        int* __restrict__ cursor, int* __restrict__ col_src,
        float* __restrict__ ea_s, int nEdges) {
    int e = blockIdx.x * blockDim.x + threadIdx.x;
    if (e < nEdges) {
        int pos = atomicAdd(&cursor[dst[e]], 1);
        col_src[pos] = src[e];
        const float* p = ea + (size_t)e * 6;
        float* q = ea_s + (size_t)pos * 6;
#pragma unroll
        for (int j = 0; j < 6; ++j) q[j] = p[j];
    }
}

// ---------------- node-side dense kernels ----------------
// h = x @ Win + b
__global__ __launch_bounds__(256) void k_in(const float* __restrict__ x,
        const float* __restrict__ w, const float* __restrict__ b,
        float* __restrict__ h, int nNodes) {
    const int lane = threadIdx.x & 63;
    const int wid  = blockIdx.x * (blockDim.x >> 6) + (threadIdx.x >> 6);
    const int nw   = gridDim.x * (blockDim.x >> 6);
    float wa[64], wb[64];
#pragma unroll
    for (int k = 0; k < 64; ++k) wa[k] = w[k * 64 + lane];
#pragma unroll
    for (int k = 0; k < 64; ++k) wb[k] = w[(64 + k) * 64 + lane];
    const float bc = b[lane];
    for (int n = wid; n < nNodes; n += nw) {
        float x0 = x[(long)n * 128 + lane];
        float x1 = x[(long)n * 128 + 64 + lane];
        float acc = bc;
#pragma unroll
        for (int k = 0; k < 64; ++k) acc += bcast(x0, k) * wa[k];
#pragma unroll
        for (int k = 0; k < 64; ++k) acc += bcast(x1, k) * wb[k];
        h[(long)n * 64 + lane] = acc;
    }
}

// P = h @ W1[0:64], Q = h @ W1[64:128]
__global__ __launch_bounds__(256) void k_pre(const float* __restrict__ h,
        const float* __restrict__ w1, float* __restrict__ P, float* __restrict__ Q,
        int nNodes) {
    const int lane = threadIdx.x & 63;
    const int wid  = blockIdx.x * (blockDim.x >> 6) + (threadIdx.x >> 6);
    const int nw   = gridDim.x * (blockDim.x >> 6);
    float wa[64], wb[64];
#pragma unroll
    for (int k = 0; k < 64; ++k) wa[k] = w1[k * 64 + lane];
#pragma unroll
    for (int k = 0; k < 64; ++k) wb[k] = w1[(64 + k) * 64 + lane];
    for (int n = wid; n < nNodes; n += nw) {
        float hv = h[(long)n * 64 + lane];
        float accP = 0.f, accQ = 0.f;
#pragma unroll
        for (int k = 0; k < 64; ++k) {
            float s = bcast(hv, k);
            accP += s * wa[k];
            accQ += s * wb[k];
        }
        P[(long)n * 64 + lane] = accP;
        Q[(long)n * 64 + lane] = accQ;
    }
}

// ---------------- edge kernel: wave per dst node, CSR, no atomics ----------------
#define M1_STRIDE 72   // ushorts; 144B rows -> 2-way bank aliasing (free)

__global__ __launch_bounds__(256) void k_edge(const float* __restrict__ P,
        const float* __restrict__ Q, const float* __restrict__ ea_s,
        const int* __restrict__ col_src, const int* __restrict__ row_ptr,
        const float* __restrict__ w1e, const float* __restrict__ b1,
        const float* __restrict__ w2, const float* __restrict__ b2,
        float* __restrict__ agg, int nNodes) {
    const int lane = threadIdx.x & 63;
    const int wib  = threadIdx.x >> 6;
    const int wid  = blockIdx.x * 4 + wib;
    const int nw   = gridDim.x * 4;
    const int quad = lane >> 4;
    const int col  = lane & 15;

    __shared__ unsigned short m1b[4][16 * M1_STRIDE];
    unsigned short* __restrict__ mt = m1b[wib];

    float w1ec[6];
#pragma unroll
    for (int j = 0; j < 6; ++j) w1ec[j] = w1e[j * 64 + lane];
    const float b1c = b1[lane];

    // B fragments: W2[k][n], elem j = W2[kh*32+quad*8+j][nt*16+col], hi/lo split
    short8 bhi[4][2], blo[4][2];
#pragma unroll
    for (int nt = 0; nt < 4; ++nt)
#pragma unroll
        for (int kh = 0; kh < 2; ++kh)
#pragma unroll
            for (int j = 0; j < 8; ++j) {
                float wv = w2[(kh * 32 + quad * 8 + j) * 64 + nt * 16 + col];
                unsigned short hi = f2bf(wv);
                float whif = __uint_as_float(((unsigned int)hi) << 16);
                unsigned short lo = f2bf(wv - whif);
                bhi[nt][kh][j] = (short)hi;
                blo[nt][kh][j] = (short)lo;
            }
    float b2v[4];
#pragma unroll
    for (int nt = 0; nt < 4; ++nt) b2v[nt] = b2[nt * 16 + col];

    for (int n = wid; n < nNodes; n += nw) {
        const int start = __builtin_amdgcn_readfirstlane(row_ptr[n]);
        const int deg   = __builtin_amdgcn_readfirstlane(row_ptr[n + 1]) - start;
        float tot = 0.f;
        if (deg > 0) {
            const float Pn = P[(size_t)n * 64 + lane] + b1c;   // fixed for node
            for (int b = 0; b < deg; b += 16) {
                // stage up to 16 edge rows (clamped dup rows masked later)
#pragma unroll
                for (int j = 0; j < 16; ++j) {
                    const int idx = start + min(b + j, deg - 1);  // uniform
                    const int s = col_src[idx];
                    float t = Pn + Q[(size_t)s * 64 + lane];
                    const float* eap = ea_s + (size_t)idx * 6;
#pragma unroll
                    for (int jj = 0; jj < 6; ++jj) t = fmaf(eap[jj], w1ec[jj], t);
                    mt[j * M1_STRIDE + lane] = f2bf(fmaxf(t, 0.f));
                }
                __builtin_amdgcn_s_waitcnt(0);   // wave-local LDS drain

                // A fragments: A[m=col][k=quad*8+j]
                short8 a0 = *(const short8*)&mt[col * M1_STRIDE + quad * 8];
                short8 a1 = *(const short8*)&mt[col * M1_STRIDE + 32 + quad * 8];

                float4v acc[4];
#pragma unroll
                for (int nt = 0; nt < 4; ++nt) {
                    float4v c = {0.f, 0.f, 0.f, 0.f};
                    c = __builtin_amdgcn_mfma_f32_16x16x32_bf16(a0, bhi[nt][0], c, 0, 0, 0);
                    c = __builtin_amdgcn_mfma_f32_16x16x32_bf16(a1, bhi[nt][1], c, 0, 0, 0);
                    c = __builtin_amdgcn_mfma_f32_16x16x32_bf16(a0, blo[nt][0], c, 0, 0, 0);
                    c = __builtin_amdgcn_mfma_f32_16x16x32_bf16(a1, blo[nt][1], c, 0, 0, 0);
                    acc[nt] = c;
                }

                // m2 = relu(C+b2) per VALID row; reduce rows -> per-col sums
                float sb0 = 0.f, sb1 = 0.f, sb2 = 0.f, sb3 = 0.f;
#pragma unroll
                for (int r = 0; r < 4; ++r) {
                    const bool valid = (b + quad * 4 + r) < deg;
                    sb0 += valid ? fmaxf(acc[0][r] + b2v[0], 0.f) : 0.f;
                    sb1 += valid ? fmaxf(acc[1][r] + b2v[1], 0.f) : 0.f;
                    sb2 += valid ? fmaxf(acc[2][r] + b2v[2], 0.f) : 0.f;
                    sb3 += valid ? fmaxf(acc[3][r] + b2v[3], 0.f) : 0.f;
                }
                // sum across the 4 quads (rows 0..15 complete)
                sb0 += __shfl_xor(sb0, 16); sb0 += __shfl_xor(sb0, 32);
                sb1 += __shfl_xor(sb1, 16); sb1 += __shfl_xor(sb1, 32);
                sb2 += __shfl_xor(sb2, 16); sb2 += __shfl_xor(sb2, 32);
                sb3 += __shfl_xor(sb3, 16); sb3 += __shfl_xor(sb3, 32);
                // lane (quad,col) keeps output column quad*16+col == lane
                tot += (quad == 0) ? sb0 : (quad == 1) ? sb1 : (quad == 2) ? sb2 : sb3;
            }
        }
        agg[(size_t)n * 64 + lane] = tot;
    }
}

// tmp = relu([h, agg] @ U1 + b1)
__global__ __launch_bounds__(256) void k_upd1(const float* __restrict__ h,
        const float* __restrict__ agg, const float* __restrict__ w,
        const float* __restrict__ b, float* __restrict__ tmp, int nNodes) {
    const int lane = threadIdx.x & 63;
    const int wid  = blockIdx.x * (blockDim.x >> 6) + (threadIdx.x >> 6);
    const int nw   = gridDim.x * (blockDim.x >> 6);
    float wa[64], wb[64];
#pragma unroll
    for (int k = 0; k < 64; ++k) wa[k] = w[k * 64 + lane];
#pragma unroll
    for (int k = 0; k < 64; ++k) wb[k] = w[(64 + k) * 64 + lane];
    const float bc = b[lane];
    for (int n = wid; n < nNodes; n += nw) {
        float hv = h[(long)n * 64 + lane];
        float av = agg[(long)n * 64 + lane];
        float acc = bc;
#pragma unroll
        for (int k = 0; k < 64; ++k) acc += bcast(hv, k) * wa[k];
#pragma unroll
        for (int k = 0; k < 64; ++k) acc += bcast(av, k) * wb[k];
        tmp[(long)n * 64 + lane] = fmaxf(acc, 0.f);
    }
}

// h += relu(tmp @ U2 + b2)
__global__ __launch_bounds__(256) void k_upd2(float* __restrict__ h,
        const float* __restrict__ tmp, const float* __restrict__ w,
        const float* __restrict__ b, int nNodes) {
    const int lane = threadIdx.x & 63;
    const int wid  = blockIdx.x * (blockDim.x >> 6) + (threadIdx.x >> 6);
    const int nw   = gridDim.x * (blockDim.x >> 6);
    float w2c[64];
#pragma unroll
    for (int k = 0; k < 64; ++k) w2c[k] = w[k * 64 + lane];
    const float bc = b[lane];
    for (int n = wid; n < nNodes; n += nw) {
        float tv = tmp[(long)n * 64 + lane];
        float acc = bc;
#pragma unroll
        for (int k = 0; k < 64; ++k) acc += bcast(tv, k) * w2c[k];
        h[(long)n * 64 + lane] += fmaxf(acc, 0.f);
    }
}

// colsum[c] += sum_n h[n][c]
__global__ __launch_bounds__(256) void k_colsum(const float* __restrict__ h,
        float* __restrict__ colsum, int nNodes) {
    const int lane = threadIdx.x & 63;
    const int wid  = blockIdx.x * 4 + (threadIdx.x >> 6);
    const int nw   = gridDim.x * 4;
    float s = 0.f;
    for (int n = wid; n < nNodes; n += nw) s += h[(long)n * 64 + lane];
    __shared__ float sm[64];
    if (threadIdx.x < 64) sm[threadIdx.x] = 0.f;
    __syncthreads();
    atomicAdd(&sm[lane], s);
    __syncthreads();
    if (threadIdx.x < 64) atomicAdd(&colsum[threadIdx.x], sm[threadIdx.x]);
}

__global__ void k_out(const float* __restrict__ colsum, const float* __restrict__ pw,
                      const float* __restrict__ pb, float* __restrict__ out, int nNodes) {
    const int lane = threadIdx.x;
    float v = colsum[lane] * pw[lane];
#pragma unroll
    for (int off = 32; off; off >>= 1) v += __shfl_down(v, off);
    if (lane == 0) out[0] = v + (float)nNodes * pb[0];
}

extern "C" void kernel_launch(void* const* d_in, const int* in_sizes, int n_in,
                              void* d_out, int out_size, void* d_ws, size_t ws_size,
                              hipStream_t stream) {
    const float* x     = (const float*)d_in[0];
    const int*   ei    = (const int*)d_in[1];
    const float* ea    = (const float*)d_in[2];
    const float* lin_w = (const float*)d_in[3];
    const float* lin_b = (const float*)d_in[4];
    const float* mw1   = (const float*)d_in[5];
    const float* mb1   = (const float*)d_in[6];
    const float* mw2   = (const float*)d_in[7];
    const float* mb2   = (const float*)d_in[8];
    const float* uw1   = (const float*)d_in[9];
    const float* ub1   = (const float*)d_in[10];
    const float* uw2   = (const float*)d_in[11];
    const float* ub2   = (const float*)d_in[12];
    const float* pw    = (const float*)d_in[13];
    const float* pb    = (const float*)d_in[14];

    const int nNodes = in_sizes[0] / 128;
    const int nEdges = in_sizes[1] / 2;
    const int* src = ei;            // edge_index[0]
    const int* dst = ei + nEdges;   // edge_index[1]

    // workspace layout (floats then ints), ~64 MB total
    float* h       = (float*)d_ws;
    float* P       = h   + (size_t)nNodes * 64;
    float* Q       = P   + (size_t)nNodes * 64;
    float* agg     = Q   + (size_t)nNodes * 64;
    float* ea_s    = agg + (size_t)nNodes * 64;
    float* colsum  = ea_s + (size_t)nEdges * 6;
    int*   deg     = (int*)(colsum + 64);
    int*   row_ptr = deg + (nNodes + 1);
    int*   cursor  = row_ptr + (nNodes + 1);
    int*   col_src = cursor + nNodes;

    const int NB_NODE = 1024;
    const int NB_EDGE = 1024;
    const int NB_FLAT = (nEdges + 255) / 256;

    // ---- CSR build (once; edge_index is layer-invariant) ----
    hipMemsetAsync(deg, 0, (size_t)(nNodes + 1) * sizeof(int), stream);
    k_hist<<<NB_FLAT, 256, 0, stream>>>(dst, deg, nEdges);
    k_scan<<<1, SCAN_T, 0, stream>>>(deg, row_ptr, cursor, nNodes);
    k_scatter<<<NB_FLAT, 256, 0, stream>>>(src, dst, ea, cursor, col_src, ea_s, nEdges);

    k_in<<<NB_NODE, 256, 0, stream>>>(x, lin_w, lin_b, h, nNodes);

    for (int l = 0; l < 4; ++l) {
        const float* w1 = mw1 + (size_t)l * 134 * 64;
        k_pre<<<NB_NODE, 256, 0, stream>>>(h, w1, P, Q, nNodes);
        k_edge<<<NB_EDGE, 256, 0, stream>>>(P, Q, ea_s, col_src, row_ptr,
            w1 + 128 * 64, mb1 + l * 64,
            mw2 + (size_t)l * 64 * 64, mb2 + l * 64, agg, nNodes);
        k_upd1<<<NB_NODE, 256, 0, stream>>>(h, agg,
            uw1 + (size_t)l * 128 * 64, ub1 + l * 64, P, nNodes);
        k_upd2<<<NB_NODE, 256, 0, stream>>>(h, P,
            uw2 + (size_t)l * 64 * 64, ub2 + l * 64, nNodes);
    }

    hipMemsetAsync(colsum, 0, 64 * sizeof(float), stream);
    k_colsum<<<512, 256, 0, stream>>>(h, colsum, nNodes);
    k_out<<<1, 64, 0, stream>>>(colsum, pw, pb, (float*)d_out, nNodes);
}

// Round 5
// 1075.848 us; speedup vs baseline: 10.4246x; 1.1129x over previous
//
#include <hip/hip_runtime.h>

// MPNN on MI355X.
//
// Algebra: msg layer-1 is linear before its relu:
//   m1 = relu(P[dst] + Q[src] + ea@W1e + b1), P = h@W1[0:64], Q = h@W1[64:128]
// R3: m2 GEMM via bf16 MFMA (W2 split hi+lo bf16 -> fp32-exact).
// R4: dst-sorted CSR, consumer-side aggregation (killed 51M fp32 atomics).
// R5: k_edge goes FLAT — each wave takes 16 consecutive CSR positions,
// segmented in-register row-reduction + one coalesced atomic per segment
// (~2/batch). Removes the per-node s_load serial chain that left everything
// idle (VALUBusy 26%, MfmaUtil 5%, HBM 10% in R4). Parallel 3-kernel scan
// (1-block scan was a hazard). upd1+upd2 fused; colsum folded into last upd.

typedef __attribute__((ext_vector_type(8))) short short8;
typedef __attribute__((ext_vector_type(4))) float float4v;

__device__ __forceinline__ float bcast(float v, int lane) {
    return __int_as_float(__builtin_amdgcn_readlane(__float_as_int(v), lane));
}

__device__ __forceinline__ unsigned short f2bf(float f) {
    unsigned int u = __float_as_uint(f);
    unsigned int r = u + 0x7fff + ((u >> 16) & 1);   // RTNE
    return (unsigned short)(r >> 16);
}

// ---------------- CSR build ----------------
__global__ __launch_bounds__(256) void k_hist(const int* __restrict__ dst,
        int* __restrict__ deg, int nEdges) {
    int e = blockIdx.x * blockDim.x + threadIdx.x;
    if (e < nEdges) atomicAdd(&deg[dst[e]], 1);
}

// block-level exclusive scan (256/block)
__global__ __launch_bounds__(256) void k_scan1(const int* __restrict__ deg,
        int* __restrict__ local, int* __restrict__ bsum, int nNodes) {
    __shared__ int sm[256];
    const int t = threadIdx.x;
    const int n = blockIdx.x * 256 + t;
    int v = (n < nNodes) ? deg[n] : 0;
    sm[t] = v;
    __syncthreads();
    for (int off = 1; off < 256; off <<= 1) {
        int u = (t >= off) ? sm[t - off] : 0;
        __syncthreads();
        sm[t] += u;
        __syncthreads();
    }
    if (n < nNodes) local[n] = sm[t] - v;          // exclusive within block
    if (t == 255) bsum[blockIdx.x] = sm[255];      // block total
}

__global__ __launch_bounds__(256) void k_scan2(int* __restrict__ bsum, int nB) {
    __shared__ int sm[256];
    const int t = threadIdx.x;
    int v = (t < nB) ? bsum[t] : 0;
    sm[t] = v;
    __syncthreads();
    for (int off = 1; off < 256; off <<= 1) {
        int u = (t >= off) ? sm[t - off] : 0;
        __syncthreads();
        sm[t] += u;
        __syncthreads();
    }
    if (t < nB) bsum[t] = sm[t] - v;               // exclusive across blocks
}

__global__ __launch_bounds__(256) void k_scan3(const int* __restrict__ local,
        const int* __restrict__ bsum, int* __restrict__ cursor, int nNodes) {
    int n = blockIdx.x * 256 + threadIdx.x;
    if (n < nNodes) cursor[n] = bsum[blockIdx.x] + local[n];
}

__global__ __launch_bounds__(256) void k_scatter(const int* __restrict__ src,
        const int* __restrict__ dst, const float* __restrict__ ea,
        int* __restrict__ cursor, int* __restrict__ col_src,
        int* __restrict__ dst_s, float* __restrict__ ea_s, int nEdges) {
    int e = blockIdx.x * blockDim.x + threadIdx.x;
    if (e < nEdges) {
        int d = dst[e];
        int pos = atomicAdd(&cursor[d], 1);
        col_src[pos] = src[e];
        dst_s[pos] = d;
        const float* p = ea + (size_t)e * 6;
        float* q = ea_s + (size_t)pos * 6;
#pragma unroll
        for (int j = 0; j < 6; ++j) q[j] = p[j];
    }
}

// ---------------- node-side dense kernels ----------------
// h = x @ Win + b
__global__ __launch_bounds__(256) void k_in(const float* __restrict__ x,
        const float* __restrict__ w, const float* __restrict__ b,
        float* __restrict__ h, int nNodes) {
    const int lane = threadIdx.x & 63;
    const int wid  = blockIdx.x * (blockDim.x >> 6) + (threadIdx.x >> 6);
    const int nw   = gridDim.x * (blockDim.x >> 6);
    float wa[64], wb[64];
#pragma unroll
    for (int k = 0; k < 64; ++k) wa[k] = w[k * 64 + lane];
#pragma unroll
    for (int k = 0; k < 64; ++k) wb[k] = w[(64 + k) * 64 + lane];
    const float bc = b[lane];
    for (int n = wid; n < nNodes; n += nw) {
        float x0 = x[(long)n * 128 + lane];
        float x1 = x[(long)n * 128 + 64 + lane];
        float acc = bc;
#pragma unroll
        for (int k = 0; k < 64; ++k) acc += bcast(x0, k) * wa[k];
#pragma unroll
        for (int k = 0; k < 64; ++k) acc += bcast(x1, k) * wb[k];
        h[(long)n * 64 + lane] = acc;
    }
}

// P = h @ W1[0:64], Q = h @ W1[64:128]
__global__ __launch_bounds__(256) void k_pre(const float* __restrict__ h,
        const float* __restrict__ w1, float* __restrict__ P, float* __restrict__ Q,
        int nNodes) {
    const int lane = threadIdx.x & 63;
    const int wid  = blockIdx.x * (blockDim.x >> 6) + (threadIdx.x >> 6);
    const int nw   = gridDim.x * (blockDim.x >> 6);
    float wa[64], wb[64];
#pragma unroll
    for (int k = 0; k < 64; ++k) wa[k] = w1[k * 64 + lane];
#pragma unroll
    for (int k = 0; k < 64; ++k) wb[k] = w1[(64 + k) * 64 + lane];
    for (int n = wid; n < nNodes; n += nw) {
        float hv = h[(long)n * 64 + lane];
        float accP = 0.f, accQ = 0.f;
#pragma unroll
        for (int k = 0; k < 64; ++k) {
            float s = bcast(hv, k);
            accP += s * wa[k];
            accQ += s * wb[k];
        }
        P[(long)n * 64 + lane] = accP;
        Q[(long)n * 64 + lane] = accQ;
    }
}

// ---------------- edge kernel: flat 16-edge batches over sorted CSR ----------------
#define M1_STRIDE 72   // ushorts; 144B rows -> 2-way bank aliasing (free)

__global__ __launch_bounds__(256) void k_edge(const float* __restrict__ P,
        const float* __restrict__ Q, const float* __restrict__ ea_s,
        const int* __restrict__ col_src, const int* __restrict__ dst_s,
        const float* __restrict__ w1e, const float* __restrict__ b1,
        const float* __restrict__ w2, const float* __restrict__ b2,
        float* __restrict__ agg, int nEdges) {
    const int lane = threadIdx.x & 63;
    const int wib  = threadIdx.x >> 6;
    const int wid  = blockIdx.x * 4 + wib;
    const int nw   = gridDim.x * 4;
    const int quad = lane >> 4;
    const int col  = lane & 15;

    __shared__ unsigned short m1b[4][16 * M1_STRIDE];
    unsigned short* __restrict__ mt = m1b[wib];

    float w1ec[6];
#pragma unroll
    for (int j = 0; j < 6; ++j) w1ec[j] = w1e[j * 64 + lane];
    const float b1c = b1[lane];

    // B fragments: W2[k][n], elem j = W2[kh*32+quad*8+j][nt*16+col], hi/lo split
    short8 bhi[4][2], blo[4][2];
#pragma unroll
    for (int nt = 0; nt < 4; ++nt)
#pragma unroll
        for (int kh = 0; kh < 2; ++kh)
#pragma unroll
            for (int j = 0; j < 8; ++j) {
                float wv = w2[(kh * 32 + quad * 8 + j) * 64 + nt * 16 + col];
                unsigned short hi = f2bf(wv);
                float whif = __uint_as_float(((unsigned int)hi) << 16);
                unsigned short lo = f2bf(wv - whif);
                bhi[nt][kh][j] = (short)hi;
                blo[nt][kh][j] = (short)lo;
            }
    float b2v[4];
#pragma unroll
    for (int nt = 0; nt < 4; ++nt) b2v[nt] = b2[nt * 16 + col];

    const int nBatch = (nEdges + 15) >> 4;
    for (int bt = wid; bt < nBatch; bt += nw) {
        const int base = __builtin_amdgcn_readfirstlane(bt << 4);

        // scalar row metadata (contiguous -> wide s_loads)
        int sj[16], dj[16];
#pragma unroll
        for (int j = 0; j < 16; ++j) {
            const int idx = min(base + j, nEdges - 1);
            sj[j] = col_src[idx];
            dj[j] = dst_s[idx];
        }
        // segment-boundary mask (static indexing only -> stays scalar)
        unsigned bmask = 1u | (1u << 16);
#pragma unroll
        for (int j = 1; j < 16; ++j) bmask |= (dj[j] != dj[j - 1]) ? (1u << j) : 0u;

        // ---- stage 16 rows: m1 -> bf16 -> LDS ----
#pragma unroll
        for (int j = 0; j < 16; ++j) {
            const int idx = min(base + j, nEdges - 1);
            float t = P[(size_t)dj[j] * 64 + lane] + Q[(size_t)sj[j] * 64 + lane] + b1c;
            const float* eap = ea_s + (size_t)idx * 6;
#pragma unroll
            for (int jj = 0; jj < 6; ++jj) t = fmaf(eap[jj], w1ec[jj], t);
            mt[j * M1_STRIDE + lane] = f2bf(fmaxf(t, 0.f));
        }
        __builtin_amdgcn_s_waitcnt(0);   // wave-local LDS drain

        // A fragments: A[m=col][k=quad*8+j]
        short8 a0 = *(const short8*)&mt[col * M1_STRIDE + quad * 8];
        short8 a1 = *(const short8*)&mt[col * M1_STRIDE + 32 + quad * 8];

        float4v acc[4];
#pragma unroll
        for (int nt = 0; nt < 4; ++nt) {
            float4v c = {0.f, 0.f, 0.f, 0.f};
            c = __builtin_amdgcn_mfma_f32_16x16x32_bf16(a0, bhi[nt][0], c, 0, 0, 0);
            c = __builtin_amdgcn_mfma_f32_16x16x32_bf16(a1, bhi[nt][1], c, 0, 0, 0);
            c = __builtin_amdgcn_mfma_f32_16x16x32_bf16(a0, blo[nt][0], c, 0, 0, 0);
            c = __builtin_amdgcn_mfma_f32_16x16x32_bf16(a1, blo[nt][1], c, 0, 0, 0);
            acc[nt] = c;
        }

        // ---- segmented reduce over rows (sorted by dst) + coalesced atomic ----
        int r0 = 0;
        while (r0 < 16) {
            const int nid = dst_s[min(base + r0, nEdges - 1)];   // scalar reload
            const int r1 = r0 + 1 + __builtin_ctz(bmask >> (r0 + 1));
            float s0 = 0.f, s1 = 0.f, s2 = 0.f, s3 = 0.f;
#pragma unroll
            for (int r = 0; r < 4; ++r) {
                const int row = quad * 4 + r;
                const bool v = (row >= r0) && (row < r1) && (base + row < nEdges);
                s0 += v ? fmaxf(acc[0][r] + b2v[0], 0.f) : 0.f;
                s1 += v ? fmaxf(acc[1][r] + b2v[1], 0.f) : 0.f;
                s2 += v ? fmaxf(acc[2][r] + b2v[2], 0.f) : 0.f;
                s3 += v ? fmaxf(acc[3][r] + b2v[3], 0.f) : 0.f;
            }
            s0 += __shfl_xor(s0, 16); s0 += __shfl_xor(s0, 32);
            s1 += __shfl_xor(s1, 16); s1 += __shfl_xor(s1, 32);
            s2 += __shfl_xor(s2, 16); s2 += __shfl_xor(s2, 32);
            s3 += __shfl_xor(s3, 16); s3 += __shfl_xor(s3, 32);
            const float tot = (quad == 0) ? s0 : (quad == 1) ? s1 : (quad == 2) ? s2 : s3;
            atomicAdd(&agg[(size_t)nid * 64 + lane], tot);   // 64 lanes = 64 cols
            r0 = r1;
        }
    }
}

// fused: tv = relu([h,agg]@U1+b1); h += relu(tv@U2+b2); optional colsum
__global__ __launch_bounds__(256) void k_upd(float* __restrict__ h,
        const float* __restrict__ agg, const float* __restrict__ w1,
        const float* __restrict__ b1, const float* __restrict__ w2,
        const float* __restrict__ b2, float* __restrict__ colsum,
        int nNodes, int doCS) {
    const int lane = threadIdx.x & 63;
    const int wid  = blockIdx.x * (blockDim.x >> 6) + (threadIdx.x >> 6);
    const int nw   = gridDim.x * (blockDim.x >> 6);
    float wa[64], wb[64], wc[64];
#pragma unroll
    for (int k = 0; k < 64; ++k) wa[k] = w1[k * 64 + lane];
#pragma unroll
    for (int k = 0; k < 64; ++k) wb[k] = w1[(64 + k) * 64 + lane];
#pragma unroll
    for (int k = 0; k < 64; ++k) wc[k] = w2[k * 64 + lane];
    const float bc1 = b1[lane];
    const float bc2 = b2[lane];
    float cs = 0.f;
    for (int n = wid; n < nNodes; n += nw) {
        float hv = h[(long)n * 64 + lane];
        float av = agg[(long)n * 64 + lane];
        float a1 = bc1;
#pragma unroll
        for (int k = 0; k < 64; ++k) a1 += bcast(hv, k) * wa[k];
#pragma unroll
        for (int k = 0; k < 64; ++k) a1 += bcast(av, k) * wb[k];
        const float tv = fmaxf(a1, 0.f);
        float a2 = bc2;
#pragma unroll
        for (int k = 0; k < 64; ++k) a2 += bcast(tv, k) * wc[k];
        const float hn = hv + fmaxf(a2, 0.f);
        h[(long)n * 64 + lane] = hn;
        cs += hn;
    }
    if (doCS) atomicAdd(&colsum[lane], cs);
}

__global__ void k_out(const float* __restrict__ colsum, const float* __restrict__ pw,
                      const float* __restrict__ pb, float* __restrict__ out, int nNodes) {
    const int lane = threadIdx.x;
    float v = colsum[lane] * pw[lane];
#pragma unroll
    for (int off = 32; off; off >>= 1) v += __shfl_down(v, off);
    if (lane == 0) out[0] = v + (float)nNodes * pb[0];
}

extern "C" void kernel_launch(void* const* d_in, const int* in_sizes, int n_in,
                              void* d_out, int out_size, void* d_ws, size_t ws_size,
                              hipStream_t stream) {
    const float* x     = (const float*)d_in[0];
    const int*   ei    = (const int*)d_in[1];
    const float* ea    = (const float*)d_in[2];
    const float* lin_w = (const float*)d_in[3];
    const float* lin_b = (const float*)d_in[4];
    const float* mw1   = (const float*)d_in[5];
    const float* mb1   = (const float*)d_in[6];
    const float* mw2   = (const float*)d_in[7];
    const float* mb2   = (const float*)d_in[8];
    const float* uw1   = (const float*)d_in[9];
    const float* ub1   = (const float*)d_in[10];
    const float* uw2   = (const float*)d_in[11];
    const float* ub2   = (const float*)d_in[12];
    const float* pw    = (const float*)d_in[13];
    const float* pb    = (const float*)d_in[14];

    const int nNodes = in_sizes[0] / 128;
    const int nEdges = in_sizes[1] / 2;
    const int* src = ei;            // edge_index[0]
    const int* dst = ei + nEdges;   // edge_index[1]

    // workspace layout
    float* h       = (float*)d_ws;
    float* P       = h   + (size_t)nNodes * 64;
    float* Q       = P   + (size_t)nNodes * 64;
    float* agg     = Q   + (size_t)nNodes * 64;
    float* ea_s    = agg + (size_t)nNodes * 64;
    float* colsum  = ea_s + (size_t)nEdges * 6;
    int*   deg     = (int*)(colsum + 64);
    int*   cursor  = deg + nNodes;
    int*   local   = cursor + nNodes;
    int*   bsum    = local + nNodes;
    int*   col_src = bsum + 256;
    int*   dst_s   = col_src + nEdges;

    const int NB_NODE = 1024;
    const int NB_EDGE = 2048;
    const int NB_FLAT = (nEdges + 255) / 256;
    const int NB_SCAN = (nNodes + 255) / 256;

    // ---- CSR build (once; edge_index is layer-invariant) ----
    hipMemsetAsync(deg, 0, (size_t)nNodes * sizeof(int), stream);
    hipMemsetAsync(colsum, 0, 64 * sizeof(float), stream);
    k_hist<<<NB_FLAT, 256, 0, stream>>>(dst, deg, nEdges);
    k_scan1<<<NB_SCAN, 256, 0, stream>>>(deg, local, bsum, nNodes);
    k_scan2<<<1, 256, 0, stream>>>(bsum, NB_SCAN);
    k_scan3<<<NB_SCAN, 256, 0, stream>>>(local, bsum, cursor, nNodes);
    k_scatter<<<NB_FLAT, 256, 0, stream>>>(src, dst, ea, cursor, col_src, dst_s, ea_s, nEdges);

    k_in<<<NB_NODE, 256, 0, stream>>>(x, lin_w, lin_b, h, nNodes);

    for (int l = 0; l < 4; ++l) {
        const float* w1 = mw1 + (size_t)l * 134 * 64;
        k_pre<<<NB_NODE, 256, 0, stream>>>(h, w1, P, Q, nNodes);
        hipMemsetAsync(agg, 0, (size_t)nNodes * 64 * sizeof(float), stream);
        k_edge<<<NB_EDGE, 256, 0, stream>>>(P, Q, ea_s, col_src, dst_s,
            w1 + 128 * 64, mb1 + l * 64,
            mw2 + (size_t)l * 64 * 64, mb2 + l * 64, agg, nEdges);
        k_upd<<<NB_NODE, 256, 0, stream>>>(h, agg,
            uw1 + (size_t)l * 128 * 64, ub1 + l * 64,
            uw2 + (size_t)l * 64 * 64, ub2 + l * 64,
            colsum, nNodes, (l == 3) ? 1 : 0);
    }

    k_out<<<1, 64, 0, stream>>>(colsum, pw, pb, (float*)d_out, nNodes);
}

// Round 7
// 805.998 us; speedup vs baseline: 13.9147x; 1.3348x over previous
//
#include <hip/hip_runtime.h>

// MPNN on MI355X.
//
// Algebra: msg layer-1 is linear before its relu:
//   m1 = relu(P[dst] + Q[src] + ea@W1e + b1), P = h@W1[0:64], Q = h@W1[64:128]
// R3: m2 GEMM via bf16 MFMA (A plain bf16 = random rounding, W hi+lo bf16 =
//     no systematic error; absmax stayed 0.0).
// R4: dst-sorted CSR, consumer-side aggregation (killed 51M fp32 atomics).
// R5: flat 16-edge batches + segmented reduce + per-segment coalesced atomic.
// R6: k_edge 32-edge batches; metadata via vector loads + v_readlane (kills
//     the per-batch s_load serial chain and per-segment dst_s reload);
//     segment mask via one __ballot. Node GEMMs (k_in/k_pre/k_upd1/k_upd2)
//     MFMA-ized with the same bf16-A + hi/lo-W recipe.
// R7: fix compile error (address of ext_vector element) — wsplit returns a
//     pair by value; vector elements assigned by subscript.

typedef __attribute__((ext_vector_type(8))) short short8;
typedef __attribute__((ext_vector_type(4))) float float4v;

__device__ __forceinline__ unsigned short f2bf(float f) {
    unsigned int u = __float_as_uint(f);
    unsigned int r = u + 0x7fff + ((u >> 16) & 1);   // RTNE
    return (unsigned short)(r >> 16);
}

#define MFMA16(a, b, c) __builtin_amdgcn_mfma_f32_16x16x32_bf16(a, b, c, 0, 0, 0)

struct bfpair { short hi, lo; };
__device__ __forceinline__ bfpair wsplit(float wv) {
    bfpair p;
    unsigned short h = f2bf(wv);
    float hf = __uint_as_float(((unsigned int)h) << 16);
    p.hi = (short)h;
    p.lo = (short)f2bf(wv - hf);
    return p;
}

// ---------------- CSR build ----------------
__global__ __launch_bounds__(256) void k_hist(const int* __restrict__ dst,
        int* __restrict__ deg, int nEdges) {
    int e = blockIdx.x * blockDim.x + threadIdx.x;
    if (e < nEdges) atomicAdd(&deg[dst[e]], 1);
}

__global__ __launch_bounds__(256) void k_scan1(const int* __restrict__ deg,
        int* __restrict__ local, int* __restrict__ bsum, int nNodes) {
    __shared__ int sm[256];
    const int t = threadIdx.x;
    const int n = blockIdx.x * 256 + t;
    int v = (n < nNodes) ? deg[n] : 0;
    sm[t] = v;
    __syncthreads();
    for (int off = 1; off < 256; off <<= 1) {
        int u = (t >= off) ? sm[t - off] : 0;
        __syncthreads();
        sm[t] += u;
        __syncthreads();
    }
    if (n < nNodes) local[n] = sm[t] - v;
    if (t == 255) bsum[blockIdx.x] = sm[255];
}

__global__ __launch_bounds__(256) void k_scan2(int* __restrict__ bsum, int nB) {
    __shared__ int sm[256];
    const int t = threadIdx.x;
    int v = (t < nB) ? bsum[t] : 0;
    sm[t] = v;
    __syncthreads();
    for (int off = 1; off < 256; off <<= 1) {
        int u = (t >= off) ? sm[t - off] : 0;
        __syncthreads();
        sm[t] += u;
        __syncthreads();
    }
    if (t < nB) bsum[t] = sm[t] - v;
}

__global__ __launch_bounds__(256) void k_scan3(const int* __restrict__ local,
        const int* __restrict__ bsum, int* __restrict__ cursor, int nNodes) {
    int n = blockIdx.x * 256 + threadIdx.x;
    if (n < nNodes) cursor[n] = bsum[blockIdx.x] + local[n];
}

__global__ __launch_bounds__(256) void k_scatter(const int* __restrict__ src,
        const int* __restrict__ dst, const float* __restrict__ ea,
        int* __restrict__ cursor, int* __restrict__ col_src,
        int* __restrict__ dst_s, float* __restrict__ ea_s, int nEdges) {
    int e = blockIdx.x * blockDim.x + threadIdx.x;
    if (e < nEdges) {
        int d = dst[e];
        int pos = atomicAdd(&cursor[d], 1);
        col_src[pos] = src[e];
        dst_s[pos] = d;
        const float* p = ea + (size_t)e * 6;
        float* q = ea_s + (size_t)pos * 6;
#pragma unroll
        for (int j = 0; j < 6; ++j) q[j] = p[j];
    }
}

// ---------------- node-side MFMA GEMM kernels ----------------
// Wave handles 16-node tiles; A rows staged fp32->bf16->LDS; W hi/lo in VGPRs.
// A-frag: A[m=col][k=quad*8+j]; C: col=lane&15, row=quad*4+reg (verified).

// h = x @ Win + b   (K=128, N=64)
__global__ __launch_bounds__(256) void k_in(const float* __restrict__ x,
        const float* __restrict__ w, const float* __restrict__ bia,
        float* __restrict__ h, int nNodes) {
    const int lane = threadIdx.x & 63;
    const int wib  = threadIdx.x >> 6;
    const int quad = lane >> 4, col = lane & 15;
    __shared__ unsigned short sm[4][16 * 136];
    unsigned short* __restrict__ mt = sm[wib];

    short8 bh[4][4], bl[4][4];
#pragma unroll
    for (int nt = 0; nt < 4; ++nt)
#pragma unroll
        for (int kf = 0; kf < 4; ++kf)
#pragma unroll
            for (int j = 0; j < 8; ++j) {
                bfpair p = wsplit(w[(kf * 32 + quad * 8 + j) * 64 + nt * 16 + col]);
                bh[nt][kf][j] = p.hi;
                bl[nt][kf][j] = p.lo;
            }
    float bv[4];
#pragma unroll
    for (int nt = 0; nt < 4; ++nt) bv[nt] = bia[nt * 16 + col];

    const int nTiles = (nNodes + 15) >> 4;
    const int wid = blockIdx.x * 4 + wib;
    const int nw  = gridDim.x * 4;
    for (int tile = wid; tile < nTiles; tile += nw) {
        const int base = tile * 16;
#pragma unroll
        for (int j = 0; j < 16; ++j) {
            int row = min(base + j, nNodes - 1);
            mt[j * 136 + lane]      = f2bf(x[(size_t)row * 128 + lane]);
            mt[j * 136 + 64 + lane] = f2bf(x[(size_t)row * 128 + 64 + lane]);
        }
        __builtin_amdgcn_s_waitcnt(0);
        short8 a[4];
#pragma unroll
        for (int kf = 0; kf < 4; ++kf)
            a[kf] = *(const short8*)&mt[col * 136 + kf * 32 + quad * 8];
#pragma unroll
        for (int nt = 0; nt < 4; ++nt) {
            float4v c = {0.f, 0.f, 0.f, 0.f};
#pragma unroll
            for (int kf = 0; kf < 4; ++kf) c = MFMA16(a[kf], bh[nt][kf], c);
#pragma unroll
            for (int kf = 0; kf < 4; ++kf) c = MFMA16(a[kf], bl[nt][kf], c);
#pragma unroll
            for (int r = 0; r < 4; ++r) {
                int row = base + quad * 4 + r;
                if (row < nNodes)
                    h[(size_t)row * 64 + nt * 16 + col] = c[r] + bv[nt];
            }
        }
    }
}

// [P|Q] = h @ [W1[0:64] | W1[64:128]]   (K=64, N=128)
__global__ __launch_bounds__(256) void k_pre(const float* __restrict__ h,
        const float* __restrict__ w1, float* __restrict__ P, float* __restrict__ Q,
        int nNodes) {
    const int lane = threadIdx.x & 63;
    const int wib  = threadIdx.x >> 6;
    const int quad = lane >> 4, col = lane & 15;
    __shared__ unsigned short sm[4][16 * 72];
    unsigned short* __restrict__ mt = sm[wib];

    short8 bh[8][2], bl[8][2];
#pragma unroll
    for (int nt = 0; nt < 8; ++nt)
#pragma unroll
        for (int kf = 0; kf < 2; ++kf)
#pragma unroll
            for (int j = 0; j < 8; ++j) {
                int k = kf * 32 + quad * 8 + j;
                float wv = (nt < 4) ? w1[k * 64 + nt * 16 + col]
                                    : w1[(64 + k) * 64 + (nt - 4) * 16 + col];
                bfpair p = wsplit(wv);
                bh[nt][kf][j] = p.hi;
                bl[nt][kf][j] = p.lo;
            }

    const int nTiles = (nNodes + 15) >> 4;
    const int wid = blockIdx.x * 4 + wib;
    const int nw  = gridDim.x * 4;
    for (int tile = wid; tile < nTiles; tile += nw) {
        const int base = tile * 16;
#pragma unroll
        for (int j = 0; j < 16; ++j) {
            int row = min(base + j, nNodes - 1);
            mt[j * 72 + lane] = f2bf(h[(size_t)row * 64 + lane]);
        }
        __builtin_amdgcn_s_waitcnt(0);
        short8 a0 = *(const short8*)&mt[col * 72 + quad * 8];
        short8 a1 = *(const short8*)&mt[col * 72 + 32 + quad * 8];
#pragma unroll
        for (int nt = 0; nt < 8; ++nt) {
            float4v c = {0.f, 0.f, 0.f, 0.f};
            c = MFMA16(a0, bh[nt][0], c);
            c = MFMA16(a1, bh[nt][1], c);
            c = MFMA16(a0, bl[nt][0], c);
            c = MFMA16(a1, bl[nt][1], c);
            float* __restrict__ outp = (nt < 4) ? P : Q;
            const int nc = (nt & 3) * 16 + col;
#pragma unroll
            for (int r = 0; r < 4; ++r) {
                int row = base + quad * 4 + r;
                if (row < nNodes) outp[(size_t)row * 64 + nc] = c[r];
            }
        }
    }
}

// tv = relu([h|agg] @ U1 + b1)   (K=128, N=64)
__global__ __launch_bounds__(256) void k_upd1(const float* __restrict__ h,
        const float* __restrict__ agg, const float* __restrict__ u1,
        const float* __restrict__ b1, float* __restrict__ tv, int nNodes) {
    const int lane = threadIdx.x & 63;
    const int wib  = threadIdx.x >> 6;
    const int quad = lane >> 4, col = lane & 15;
    __shared__ unsigned short sm[4][16 * 136];
    unsigned short* __restrict__ mt = sm[wib];

    short8 bh[4][4], bl[4][4];
#pragma unroll
    for (int nt = 0; nt < 4; ++nt)
#pragma unroll
        for (int kf = 0; kf < 4; ++kf)
#pragma unroll
            for (int j = 0; j < 8; ++j) {
                bfpair p = wsplit(u1[(kf * 32 + quad * 8 + j) * 64 + nt * 16 + col]);
                bh[nt][kf][j] = p.hi;
                bl[nt][kf][j] = p.lo;
            }
    float bv[4];
#pragma unroll
    for (int nt = 0; nt < 4; ++nt) bv[nt] = b1[nt * 16 + col];

    const int nTiles = (nNodes + 15) >> 4;
    const int wid = blockIdx.x * 4 + wib;
    const int nw  = gridDim.x * 4;
    for (int tile = wid; tile < nTiles; tile += nw) {
        const int base = tile * 16;
#pragma unroll
        for (int j = 0; j < 16; ++j) {
            int row = min(base + j, nNodes - 1);
            mt[j * 136 + lane]      = f2bf(h[(size_t)row * 64 + lane]);
            mt[j * 136 + 64 + lane] = f2bf(agg[(size_t)row * 64 + lane]);
        }
        __builtin_amdgcn_s_waitcnt(0);
        short8 a[4];
#pragma unroll
        for (int kf = 0; kf < 4; ++kf)
            a[kf] = *(const short8*)&mt[col * 136 + kf * 32 + quad * 8];
#pragma unroll
        for (int nt = 0; nt < 4; ++nt) {
            float4v c = {0.f, 0.f, 0.f, 0.f};
#pragma unroll
            for (int kf = 0; kf < 4; ++kf) c = MFMA16(a[kf], bh[nt][kf], c);
#pragma unroll
            for (int kf = 0; kf < 4; ++kf) c = MFMA16(a[kf], bl[nt][kf], c);
#pragma unroll
            for (int r = 0; r < 4; ++r) {
                int row = base + quad * 4 + r;
                if (row < nNodes)
                    tv[(size_t)row * 64 + nt * 16 + col] = fmaxf(c[r] + bv[nt], 0.f);
            }
        }
    }
}

// h += relu(tv @ U2 + b2); optional colsum of new h   (K=64, N=64)
__global__ __launch_bounds__(256) void k_upd2(float* __restrict__ h,
        const float* __restrict__ tv, const float* __restrict__ u2,
        const float* __restrict__ b2, float* __restrict__ colsum,
        int nNodes, int doCS) {
    const int lane = threadIdx.x & 63;
    const int wib  = threadIdx.x >> 6;
    const int quad = lane >> 4, col = lane & 15;
    __shared__ unsigned short sm[4][16 * 72];
    unsigned short* __restrict__ mt = sm[wib];

    short8 bh[4][2], bl[4][2];
#pragma unroll
    for (int nt = 0; nt < 4; ++nt)
#pragma unroll
        for (int kf = 0; kf < 2; ++kf)
#pragma unroll
            for (int j = 0; j < 8; ++j) {
                bfpair p = wsplit(u2[(kf * 32 + quad * 8 + j) * 64 + nt * 16 + col]);
                bh[nt][kf][j] = p.hi;
                bl[nt][kf][j] = p.lo;
            }
    float bv[4];
#pragma unroll
    for (int nt = 0; nt < 4; ++nt) bv[nt] = b2[nt * 16 + col];

    float cs0 = 0.f, cs1 = 0.f, cs2 = 0.f, cs3 = 0.f;
    const int nTiles = (nNodes + 15) >> 4;
    const int wid = blockIdx.x * 4 + wib;
    const int nw  = gridDim.x * 4;
    for (int tile = wid; tile < nTiles; tile += nw) {
        const int base = tile * 16;
#pragma unroll
        for (int j = 0; j < 16; ++j) {
            int row = min(base + j, nNodes - 1);
            mt[j * 72 + lane] = f2bf(tv[(size_t)row * 64 + lane]);
        }
        __builtin_amdgcn_s_waitcnt(0);
        short8 a0 = *(const short8*)&mt[col * 72 + quad * 8];
        short8 a1 = *(const short8*)&mt[col * 72 + 32 + quad * 8];
#pragma unroll
        for (int nt = 0; nt < 4; ++nt) {
            float4v c = {0.f, 0.f, 0.f, 0.f};
            c = MFMA16(a0, bh[nt][0], c);
            c = MFMA16(a1, bh[nt][1], c);
            c = MFMA16(a0, bl[nt][0], c);
            c = MFMA16(a1, bl[nt][1], c);
#pragma unroll
            for (int r = 0; r < 4; ++r) {
                int row = base + quad * 4 + r;
                if (row < nNodes) {
                    float* hp = &h[(size_t)row * 64 + nt * 16 + col];
                    float hn = *hp + fmaxf(c[r] + bv[nt], 0.f);
                    *hp = hn;
                    cs0 += (nt == 0) ? hn : 0.f;
                    cs1 += (nt == 1) ? hn : 0.f;
                    cs2 += (nt == 2) ? hn : 0.f;
                    cs3 += (nt == 3) ? hn : 0.f;
                }
            }
        }
    }
    if (doCS) {
        cs0 += __shfl_xor(cs0, 16); cs0 += __shfl_xor(cs0, 32);
        cs1 += __shfl_xor(cs1, 16); cs1 += __shfl_xor(cs1, 32);
        cs2 += __shfl_xor(cs2, 16); cs2 += __shfl_xor(cs2, 32);
        cs3 += __shfl_xor(cs3, 16); cs3 += __shfl_xor(cs3, 32);
        const float tot = (quad == 0) ? cs0 : (quad == 1) ? cs1
                        : (quad == 2) ? cs2 : cs3;
        atomicAdd(&colsum[lane], tot);   // lane == quad*16+col
    }
}

// ---------------- edge kernel: flat 32-edge batches over sorted CSR ----------------
#define EST 72   // ushorts per staged row

__global__ __launch_bounds__(256) void k_edge(const float* __restrict__ P,
        const float* __restrict__ Q, const float* __restrict__ ea_s,
        const int* __restrict__ col_src, const int* __restrict__ dst_s,
        const float* __restrict__ w1e, const float* __restrict__ b1,
        const float* __restrict__ w2, const float* __restrict__ b2,
        float* __restrict__ agg, int nEdges) {
    const int lane = threadIdx.x & 63;
    const int wib  = threadIdx.x >> 6;
    const int wid  = blockIdx.x * 4 + wib;
    const int nw   = gridDim.x * 4;
    const int quad = lane >> 4;
    const int col  = lane & 15;

    __shared__ unsigned short m1b[4][32 * EST];
    unsigned short* __restrict__ mt = m1b[wib];

    float w1ec[6];
#pragma unroll
    for (int j = 0; j < 6; ++j) w1ec[j] = w1e[j * 64 + lane];
    const float b1c = b1[lane];

    short8 bhi[4][2], blo[4][2];
#pragma unroll
    for (int nt = 0; nt < 4; ++nt)
#pragma unroll
        for (int kf = 0; kf < 2; ++kf)
#pragma unroll
            for (int j = 0; j < 8; ++j) {
                bfpair p = wsplit(w2[(kf * 32 + quad * 8 + j) * 64 + nt * 16 + col]);
                bhi[nt][kf][j] = p.hi;
                blo[nt][kf][j] = p.lo;
            }
    float b2v[4];
#pragma unroll
    for (int nt = 0; nt < 4; ++nt) b2v[nt] = b2[nt * 16 + col];

    const int nBatch = (nEdges + 31) >> 5;
    for (int bt = wid; bt < nBatch; bt += nw) {
        const int base = __builtin_amdgcn_readfirstlane(bt << 5);
        const int li = lane & 31;
        const int gidx = min(base + li, nEdges - 1);
        const int vdj = dst_s[gidx];          // row li's dst (lanes 32-63 dup)
        const int vsj = col_src[gidx];        // row li's src
        const int vprev = __shfl_up(vdj, 1);
        unsigned long long bmask =
            __ballot(lane < 32 && (li == 0 || vdj != vprev));
        bmask |= (1ull << 32) | 1ull;

        // ---- stage 32 rows: m1 -> bf16 -> LDS ----
#pragma unroll
        for (int j = 0; j < 32; ++j) {
            const int d = __builtin_amdgcn_readlane(vdj, j);
            const int s = __builtin_amdgcn_readlane(vsj, j);
            const int idx = min(base + j, nEdges - 1);   // uniform
            float t = P[(size_t)d * 64 + lane] + Q[(size_t)s * 64 + lane] + b1c;
            const float* eap = ea_s + (size_t)idx * 6;
#pragma unroll
            for (int jj = 0; jj < 6; ++jj) t = fmaf(eap[jj], w1ec[jj], t);
            mt[j * EST + lane] = f2bf(fmaxf(t, 0.f));
        }
        __builtin_amdgcn_s_waitcnt(0);   // wave-local LDS drain

        short8 a00 = *(const short8*)&mt[col * EST + quad * 8];
        short8 a01 = *(const short8*)&mt[col * EST + 32 + quad * 8];
        short8 a10 = *(const short8*)&mt[(16 + col) * EST + quad * 8];
        short8 a11 = *(const short8*)&mt[(16 + col) * EST + 32 + quad * 8];

        // m2 for both 16-row tiles, masked+relu'd up front
        float4v m2v[2][4];
#pragma unroll
        for (int nt = 0; nt < 4; ++nt) {
            float4v c0 = {0.f, 0.f, 0.f, 0.f};
            float4v c1 = {0.f, 0.f, 0.f, 0.f};
            c0 = MFMA16(a00, bhi[nt][0], c0);
            c0 = MFMA16(a01, bhi[nt][1], c0);
            c0 = MFMA16(a00, blo[nt][0], c0);
            c0 = MFMA16(a01, blo[nt][1], c0);
            c1 = MFMA16(a10, bhi[nt][0], c1);
            c1 = MFMA16(a11, bhi[nt][1], c1);
            c1 = MFMA16(a10, blo[nt][0], c1);
            c1 = MFMA16(a11, blo[nt][1], c1);
#pragma unroll
            for (int r = 0; r < 4; ++r) {
                const bool v0 = base + (quad * 4 + r) < nEdges;
                const bool v1 = base + 16 + (quad * 4 + r) < nEdges;
                m2v[0][nt][r] = v0 ? fmaxf(c0[r] + b2v[nt], 0.f) : 0.f;
                m2v[1][nt][r] = v1 ? fmaxf(c1[r] + b2v[nt], 0.f) : 0.f;
            }
        }

        // ---- segmented reduce + one coalesced atomic per segment ----
        int r0 = 0;
        while (r0 < 32) {
            const int nid = __builtin_amdgcn_readlane(vdj, r0);
            const int r1 = r0 + 1 + (int)__builtin_ctzll(bmask >> (r0 + 1));
            float s0 = 0.f, s1 = 0.f, s2 = 0.f, s3 = 0.f;
#pragma unroll
            for (int t = 0; t < 2; ++t)
#pragma unroll
                for (int r = 0; r < 4; ++r) {
                    const int R = t * 16 + quad * 4 + r;
                    const bool in = (R >= r0) && (R < r1);
                    s0 += in ? m2v[t][0][r] : 0.f;
                    s1 += in ? m2v[t][1][r] : 0.f;
                    s2 += in ? m2v[t][2][r] : 0.f;
                    s3 += in ? m2v[t][3][r] : 0.f;
                }
            s0 += __shfl_xor(s0, 16); s0 += __shfl_xor(s0, 32);
            s1 += __shfl_xor(s1, 16); s1 += __shfl_xor(s1, 32);
            s2 += __shfl_xor(s2, 16); s2 += __shfl_xor(s2, 32);
            s3 += __shfl_xor(s3, 16); s3 += __shfl_xor(s3, 32);
            const float tot = (quad == 0) ? s0 : (quad == 1) ? s1
                            : (quad == 2) ? s2 : s3;
            atomicAdd(&agg[(size_t)nid * 64 + lane], tot);
            r0 = r1;
        }
    }
}

__global__ void k_out(const float* __restrict__ colsum, const float* __restrict__ pw,
                      const float* __restrict__ pb, float* __restrict__ out, int nNodes) {
    const int lane = threadIdx.x;
    float v = colsum[lane] * pw[lane];
#pragma unroll
    for (int off = 32; off; off >>= 1) v += __shfl_down(v, off);
    if (lane == 0) out[0] = v + (float)nNodes * pb[0];
}

extern "C" void kernel_launch(void* const* d_in, const int* in_sizes, int n_in,
                              void* d_out, int out_size, void* d_ws, size_t ws_size,
                              hipStream_t stream) {
    const float* x     = (const float*)d_in[0];
    const int*   ei    = (const int*)d_in[1];
    const float* ea    = (const float*)d_in[2];
    const float* lin_w = (const float*)d_in[3];
    const float* lin_b = (const float*)d_in[4];
    const float* mw1   = (const float*)d_in[5];
    const float* mb1   = (const float*)d_in[6];
    const float* mw2   = (const float*)d_in[7];
    const float* mb2   = (const float*)d_in[8];
    const float* uw1   = (const float*)d_in[9];
    const float* ub1   = (const float*)d_in[10];
    const float* uw2   = (const float*)d_in[11];
    const float* ub2   = (const float*)d_in[12];
    const float* pw    = (const float*)d_in[13];
    const float* pb    = (const float*)d_in[14];

    const int nNodes = in_sizes[0] / 128;
    const int nEdges = in_sizes[1] / 2;
    const int* src = ei;            // edge_index[0]
    const int* dst = ei + nEdges;   // edge_index[1]

    // workspace layout
    float* h       = (float*)d_ws;
    float* P       = h   + (size_t)nNodes * 64;   // also reused as tv
    float* Q       = P   + (size_t)nNodes * 64;
    float* agg     = Q   + (size_t)nNodes * 64;
    float* ea_s    = agg + (size_t)nNodes * 64;
    float* colsum  = ea_s + (size_t)nEdges * 6;
    int*   deg     = (int*)(colsum + 64);
    int*   cursor  = deg + nNodes;
    int*   local   = cursor + nNodes;
    int*   bsum    = local + nNodes;
    int*   col_src = bsum + 256;
    int*   dst_s   = col_src + nEdges;

    const int NB_T    = 392;                     // node-GEMM tiles: ~2/wave
    const int NB_EDGE = 2048;
    const int NB_FLAT = (nEdges + 255) / 256;
    const int NB_SCAN = (nNodes + 255) / 256;

    // ---- CSR build (once; edge_index is layer-invariant) ----
    hipMemsetAsync(deg, 0, (size_t)nNodes * sizeof(int), stream);
    hipMemsetAsync(colsum, 0, 64 * sizeof(float), stream);
    k_hist<<<NB_FLAT, 256, 0, stream>>>(dst, deg, nEdges);
    k_scan1<<<NB_SCAN, 256, 0, stream>>>(deg, local, bsum, nNodes);
    k_scan2<<<1, 256, 0, stream>>>(bsum, NB_SCAN);
    k_scan3<<<NB_SCAN, 256, 0, stream>>>(local, bsum, cursor, nNodes);
    k_scatter<<<NB_FLAT, 256, 0, stream>>>(src, dst, ea, cursor, col_src, dst_s, ea_s, nEdges);

    k_in<<<NB_T, 256, 0, stream>>>(x, lin_w, lin_b, h, nNodes);

    for (int l = 0; l < 4; ++l) {
        const float* w1 = mw1 + (size_t)l * 134 * 64;
        k_pre<<<NB_T, 256, 0, stream>>>(h, w1, P, Q, nNodes);
        hipMemsetAsync(agg, 0, (size_t)nNodes * 64 * sizeof(float), stream);
        k_edge<<<NB_EDGE, 256, 0, stream>>>(P, Q, ea_s, col_src, dst_s,
            w1 + 128 * 64, mb1 + l * 64,
            mw2 + (size_t)l * 64 * 64, mb2 + l * 64, agg, nEdges);
        k_upd1<<<NB_T, 256, 0, stream>>>(h, agg,
            uw1 + (size_t)l * 128 * 64, ub1 + l * 64, P, nNodes);
        k_upd2<<<NB_T, 256, 0, stream>>>(h, P,
            uw2 + (size_t)l * 64 * 64, ub2 + l * 64,
            colsum, nNodes, (l == 3) ? 1 : 0);
    }

    k_out<<<1, 64, 0, stream>>>(colsum, pw, pb, (float*)d_out, nNodes);
}